// Round 2
// baseline (798.783 us; speedup 1.0000x reference)
//
#include <hip/hip_runtime.h>

// Problem constants (MultiHeadAttention_79431125172249)
// All float tensors are fp32 (reference dtype); mask is int32; output fp32.
#define B_  32
#define S_  4096
#define E_  1024
#define H_  16
#define D_  64
#define NV_ 64
#define HD_ 1024   // H_*D_

typedef unsigned short ushort_t;
typedef __attribute__((ext_vector_type(8))) short  short8;   // 8 x bf16 (4 VGPRs)
typedef __attribute__((ext_vector_type(4))) float  floatx4;  // MFMA f32 acc

__device__ __forceinline__ ushort_t f2b(float f) {  // fp32 -> bf16 RNE
  union { float f; unsigned int u; } v; v.f = f;
  return (ushort_t)((v.u + 0x7FFFu + ((v.u >> 16) & 1u)) >> 16);
}
// pack two fp32 -> two bf16 (round-half-up; bias-free enough for 2% tol)
__device__ __forceinline__ unsigned int pk2(float lo, float hi) {
  union { float f; unsigned int u; } a, b; a.f = lo; b.f = hi;
  return ((a.u + 0x8000u) >> 16) | ((b.u + 0x8000u) & 0xFFFF0000u);
}

// ---------------------------------------------------------------------------
// Kernel A: q[b,h,:] = seq1[b]@Wq_h + bq_h  then  r[b,h,:] = (Wk_h @ q)/sqrt(D)
// r stored bf16 in workspace, layout [b][h][e]. bk skipped (softmax-invariant:
// it adds a per-(b,h) constant to every score in the row).
// ---------------------------------------------------------------------------
__global__ __launch_bounds__(256) void qr_kernel(
    const float* __restrict__ seq1, const float* __restrict__ Wq,
    const float* __restrict__ bq,   const float* __restrict__ Wk,
    ushort_t* __restrict__ r_bf) {
  __shared__ __align__(16) float qp[4][64];
  __shared__ __align__(16) float qv[64];
  const int b = blockIdx.x / H_, h = blockIdx.x % H_;
  const int t = threadIdx.x;
  const int d = t & 63, quarter = t >> 6;

  // stage 1: q_d = sum_e seq1[b,e] * Wq[e, h*64+d]; K=1024 split in 4 chunks
  {
    const float* s1 = seq1 + (size_t)b * E_;
    const float* wq = Wq + h * D_ + d;
    float sum = 0.f;
    const int e0 = quarter * 256;
    for (int e = e0; e < e0 + 256; ++e)
      sum += s1[e] * wq[(size_t)e * HD_];
    qp[quarter][d] = sum;
  }
  __syncthreads();
  if (t < 64) qv[t] = qp[0][t] + qp[1][t] + qp[2][t] + qp[3][t] + bq[h * D_ + t];
  __syncthreads();

  // stage 2: r_e = (1/8) * sum_d Wk[e, h*64+d] * q_d   (4 e's per thread)
  for (int i = 0; i < 4; ++i) {
    const int e = t + 256 * i;
    const float* wk = Wk + (size_t)e * HD_ + h * D_;
    float rs = 0.f;
#pragma unroll
    for (int g = 0; g < 16; ++g) {
      const float4 w4 = *(const float4*)(wk + g * 4);
      rs += w4.x * qv[g * 4 + 0] + w4.y * qv[g * 4 + 1] +
            w4.z * qv[g * 4 + 2] + w4.w * qv[g * 4 + 3];
    }
    r_bf[((size_t)b * H_ + h) * E_ + e] = f2b(rs * 0.125f);  // fold 1/sqrt(64)
  }
}

// ---------------------------------------------------------------------------
// Kernel B: flash pass over seq2. One block = (batch b, S-chunk). All 16 heads
// together. Per 16-row tile: stage fp32 X tile -> bf16 LDS, MFMA scores
// (16s x 16h, K=1024 over 4 waves), wave0 masked online-softmax, then all
// threads do the weighted row-sum c[h][e] outer-product (16h x 4e / thread).
// ---------------------------------------------------------------------------
__global__ __launch_bounds__(256) void attn_kernel(
    const float* __restrict__ seq2, const int* __restrict__ mask,
    const ushort_t* __restrict__ r_bf, float* __restrict__ cpart,
    float* __restrict__ mlpart, int NC, int TPC) {
  __shared__ __align__(16) ushort_t rS[16][1032];   // r rows per head (+pad)
  __shared__ __align__(16) ushort_t xS[16][1032];   // X tile rows, bf16
  __shared__ __align__(16) float scp[4][16][17];    // per-wave score partials
  __shared__ __align__(16) float Pt[16][16];        // p[s][h]
  __shared__ __align__(16) float mS[16], lS[16], alphaS[16];

  const int b = blockIdx.y, chunk = blockIdx.x;
  const int t = threadIdx.x;
  const int lane = t & 63, w = t >> 6;
  const int s0 = chunk * (TPC * 16);
  const int e0 = t * 4;                  // this thread's 4 e-columns

  // stage r for all 16 heads (16 x 1024 bf16)
  {
    const uint4* src = (const uint4*)(r_bf + (size_t)b * H_ * E_);
#pragma unroll
    for (int i = 0; i < 8; ++i) {
      const int f = t + 256 * i;
      *(uint4*)&rS[f >> 7][(f & 127) * 8] = src[f];
    }
  }
  if (t < 16) { mS[t] = -3e38f; lS[t] = 0.f; }

  float c[16][4];
#pragma unroll
  for (int h = 0; h < 16; ++h)
#pragma unroll
    for (int j = 0; j < 4; ++j) c[h][j] = 0.f;

  for (int it = 0; it < TPC; ++it) {
    const int st = s0 + it * 16;
    __syncthreads();  // protects xS/Pt readers of previous iteration
    // stage X tile: 16 rows x 1024 fp32 -> bf16 LDS, coalesced float4 loads
    {
      const float4* src = (const float4*)(seq2 + ((size_t)b * S_ + st) * E_);
#pragma unroll
      for (int i = 0; i < 16; ++i) {
        const int f = t + 256 * i;          // [0,4096) float4 index
        const float4 v = src[f];
        *(uint2*)&xS[f >> 8][(f & 255) * 4] =
            make_uint2(pk2(v.x, v.y), pk2(v.z, v.w));
      }
    }
    __syncthreads();

    // MFMA scores: wave w covers e in [w*256, w*256+256) -> 8 mfma k-steps
    {
      const int m = lane & 15, q = lane >> 4;
      floatx4 acc = {0.f, 0.f, 0.f, 0.f};
#pragma unroll
      for (int kk = 0; kk < 8; ++kk) {
        const int kb = w * 256 + kk * 32 + q * 8;
        short8 av  = *(const short8*)&xS[m][kb];  // A[m=s][k=e]
        short8 bvf = *(const short8*)&rS[m][kb];  // B[n=h][k=e] (K-major)
        acc = __builtin_amdgcn_mfma_f32_16x16x32_bf16(av, bvf, acc, 0, 0, 0);
      }
#pragma unroll
      for (int j = 0; j < 4; ++j)
        scp[w][q * 4 + j][m] = acc[j];  // C: col=lane&15 (=n=h), row=q*4+j (=s)
    }
    __syncthreads();

    // wave 0: reduce 4 K-partials, mask, online softmax, write P
    if (w == 0) {
      const int h = lane & 15, sg = lane >> 4;
      float sc[4];
#pragma unroll
      for (int j = 0; j < 4; ++j) {
        const int s = sg * 4 + j;
        float v = scp[0][s][h] + scp[1][s][h] + scp[2][s][h] + scp[3][s][h];
        if (mask[(size_t)b * S_ + st + s] == 0) v = -1e9f;  // match reference
        sc[j] = v;
      }
      float tm = fmaxf(fmaxf(sc[0], sc[1]), fmaxf(sc[2], sc[3]));
      tm = fmaxf(tm, __shfl_xor(tm, 16));
      tm = fmaxf(tm, __shfl_xor(tm, 32));
      const float mo = mS[h];
      const float nm = fmaxf(mo, tm);
      const float al = __expf(mo - nm);
      float ps = 0.f;
#pragma unroll
      for (int j = 0; j < 4; ++j) {
        const float p = __expf(sc[j] - nm);
        Pt[sg * 4 + j][h] = p;
        ps += p;
      }
      ps += __shfl_xor(ps, 16);
      ps += __shfl_xor(ps, 32);
      if (lane < 16) { mS[h] = nm; alphaS[h] = al; lS[h] = lS[h] * al + ps; }
    }
    __syncthreads();

    // accumulate: c[h][:] = c[h][:]*alpha[h] + sum_s P[s][h] * x[s][e0..e0+3]
    {
#pragma unroll
      for (int h = 0; h < 16; ++h) {
        const float a = alphaS[h];
        c[h][0] *= a; c[h][1] *= a; c[h][2] *= a; c[h][3] *= a;
      }
#pragma unroll
      for (int s = 0; s < 16; ++s) {
        union { uint2 v; ushort_t u[4]; } xr;
        xr.v = *(const uint2*)&xS[s][e0];
        union { unsigned int i; float f; } cv;
        cv.i = (unsigned int)xr.u[0] << 16; const float x0 = cv.f;
        cv.i = (unsigned int)xr.u[1] << 16; const float x1 = cv.f;
        cv.i = (unsigned int)xr.u[2] << 16; const float x2 = cv.f;
        cv.i = (unsigned int)xr.u[3] << 16; const float x3 = cv.f;
        float p[16];
        *(float4*)&p[0]  = *(const float4*)&Pt[s][0];
        *(float4*)&p[4]  = *(const float4*)&Pt[s][4];
        *(float4*)&p[8]  = *(const float4*)&Pt[s][8];
        *(float4*)&p[12] = *(const float4*)&Pt[s][12];
#pragma unroll
        for (int h = 0; h < 16; ++h) {
          c[h][0] += p[h] * x0; c[h][1] += p[h] * x1;
          c[h][2] += p[h] * x2; c[h][3] += p[h] * x3;
        }
      }
    }
  }

  // write chunk partials: c (f32) and (m,l) per head
  const size_t base = ((size_t)b * NC + chunk) * H_ * E_;
#pragma unroll
  for (int h = 0; h < 16; ++h)
    *(float4*)&cpart[base + (size_t)h * E_ + e0] =
        make_float4(c[h][0], c[h][1], c[h][2], c[h][3]);
  if (t < 16) {  // wave0 lanes that wrote mS/lS themselves (no race)
    mlpart[(((size_t)b * NC + chunk) * H_ + t) * 2 + 0] = mS[t];
    mlpart[(((size_t)b * NC + chunk) * H_ + t) * 2 + 1] = lS[t];
  }
}

// ---------------------------------------------------------------------------
// Kernel C: combine chunk partials for one (b,h), then out = (c/L)@Wv_h + bv_h
// ---------------------------------------------------------------------------
__global__ __launch_bounds__(256) void combine_kernel(
    const float* __restrict__ cpart, const float* __restrict__ mlpart,
    const float* __restrict__ Wv, const float* __restrict__ bvp,
    float* __restrict__ out, int NC) {
  __shared__ __align__(16) float wS[64];
  __shared__ __align__(16) float cnS[1024];
  __shared__ __align__(16) float vp[4][64];
  __shared__ float invLS;
  const int b = blockIdx.x / H_, h = blockIdx.x % H_;
  const int t = threadIdx.x;

  if (t < 64) {
    float m_i = -3e38f, l_i = 0.f;
    if (t < NC) {
      const size_t mi = (((size_t)b * NC + t) * H_ + h) * 2;
      m_i = mlpart[mi]; l_i = mlpart[mi + 1];
    }
    float M = m_i;
#pragma unroll
    for (int dlt = 1; dlt < 64; dlt <<= 1) M = fmaxf(M, __shfl_xor(M, dlt));
    const float wi = (t < NC) ? __expf(m_i - M) : 0.f;
    float Lp = l_i * wi;
#pragma unroll
    for (int dlt = 1; dlt < 64; dlt <<= 1) Lp += __shfl_xor(Lp, dlt);
    if (t < NC) wS[t] = wi;
    if (t == 0) invLS = 1.f / Lp;
  }
  __syncthreads();

  // combine c partials, normalize
  {
    const int e0 = t * 4;
    float a0 = 0.f, a1 = 0.f, a2 = 0.f, a3 = 0.f;
    for (int i = 0; i < NC; ++i) {
      const float wi = wS[i];
      const float4 v =
          *(const float4*)&cpart[(((size_t)b * NC + i) * H_ + h) * E_ + e0];
      a0 += wi * v.x; a1 += wi * v.y; a2 += wi * v.z; a3 += wi * v.w;
    }
    const float inv = invLS;
    *(float4*)&cnS[e0] = make_float4(a0 * inv, a1 * inv, a2 * inv, a3 * inv);
  }
  __syncthreads();

  // tiny GEMV: out_n = sum_e cn[e] * Wv[e, h*64+n]  (coalesced across n)
  {
    const int n = t & 63, part = t >> 6;
    const float* wv = Wv + h * NV_ + n;
    float sum = 0.f;
    const int eb = part * 256;
    for (int e = eb; e < eb + 256; ++e)
      sum += cnS[e] * wv[(size_t)e * E_];
    vp[part][n] = sum;
  }
  __syncthreads();
  if (t < 64) {
    const float o = vp[0][t] + vp[1][t] + vp[2][t] + vp[3][t] + bvp[h * NV_ + t];
    out[(size_t)b * E_ + h * NV_ + t] = o;
  }
}

// ---------------------------------------------------------------------------
extern "C" void kernel_launch(void* const* d_in, const int* in_sizes, int n_in,
                              void* d_out, int out_size, void* d_ws, size_t ws_size,
                              hipStream_t stream) {
  const float* seq1 = (const float*)d_in[0];
  const float* seq2 = (const float*)d_in[1];
  const int*   mask = (const int*)d_in[2];
  const float* Wq   = (const float*)d_in[3];
  const float* bq   = (const float*)d_in[4];
  const float* Wk   = (const float*)d_in[5];
  // d_in[6] = bk: softmax-invariant, skipped
  const float* Wv   = (const float*)d_in[7];
  const float* bv   = (const float*)d_in[8];
  float* out = (float*)d_out;

  // workspace: r_bf (1 MB bf16) | cpart (B*NC*H*E f32) | mlpart
  const size_t rbytes = (size_t)B_ * H_ * E_ * 2;
  int NC = 16;
  while (NC > 1) {
    const size_t need = rbytes + (size_t)B_ * NC * H_ * E_ * 4
                               + (size_t)B_ * NC * H_ * 2 * 4;
    if (need <= ws_size) break;
    NC >>= 1;
  }
  const int TPC = (S_ / NC) / 16;
  ushort_t* r_bf = (ushort_t*)d_ws;
  float* cpart   = (float*)((char*)d_ws + rbytes);
  float* mlpart  = (float*)((char*)d_ws + rbytes + (size_t)B_ * NC * H_ * E_ * 4);

  qr_kernel<<<dim3(B_ * H_), dim3(256), 0, stream>>>(seq1, Wq, bq, Wk, r_bf);
  attn_kernel<<<dim3(NC, B_), dim3(256), 0, stream>>>(seq2, mask, r_bf, cpart,
                                                      mlpart, NC, TPC);
  combine_kernel<<<dim3(B_ * H_), dim3(256), 0, stream>>>(cpart, mlpart, Wv, bv,
                                                          out, NC);
}